// Round 1
// baseline (485.838 us; speedup 1.0000x reference)
//
#include <hip/hip_runtime.h>

// GConvGRU (ChebConv K=1) + ReLU + Linear, fully fused, H0 = 0:
//   Z  = sigmoid(x@Wxz + bxz + bhz)
//   Ht = tanh(x@Wxh + bxh + bhh)          (R-gate cancels: R*H0 = 0)
//   out = relu((1-Z)*Ht) @ Wlin + blin
// edge_index / edge_weight mathematically unused (K=1) -> never read.
//
// R2 changes vs R1 (theory: latency/occupancy-bound, not pipe-bound):
//  * NPT 4 -> 2: feature regs 64 -> 32 VGPR, accumulators 32 -> 4 VGPR
//    (per-j epilogue keeps only one j's accs live). Target <=64 VGPR
//    => 8 waves/SIMD (vs ~4), and 1954 blocks (vs 977) for a finer tail.
//  * "#pragma unroll 1" removed: full unroll over j lets the scheduler
//    hoist the next j's scalar weight loads under the current j's
//    pk-FMA chain + transcendentals (R1 stalled on lgkmcnt at each of
//    8 chunk boundaries).
//  * x features packed ONCE into v2f node-pairs (32 v_movs total, was
//    rebuilt per chunk).
// Math identical to R1 -> absmax unchanged.

typedef float v2f __attribute__((ext_vector_type(2)));

constexpr int F   = 16;  // F_IN
constexpr int HD  = 32;  // HID
constexpr int NPT = 2;   // nodes per thread (one v2f pair)

__global__ __launch_bounds__(256, 4) void gru_fused(
    const float* __restrict__ x,
    const float* __restrict__ Wxz, const float* __restrict__ bxz,
    const float* __restrict__ bhz,
    const float* __restrict__ Wxh, const float* __restrict__ bxh,
    const float* __restrict__ bhh,
    const float* __restrict__ Wlin, const float* __restrict__ blin,
    float* __restrict__ out, int n)
{
    const int t = blockIdx.x * 256 + threadIdx.x;
    const int base = t * NPT;
    if (base >= n) return;  // n % 2 == 0, pair guard exact

    // Load both nodes' 16 features as float4s, pack into 16 v2f pairs:
    // xp[k] = { x[node0][k], x[node1][k] }  (32 VGPRs, live whole kernel)
    v2f xp[F];
    {
        float a[F], b[F];
        const float4* p0 = reinterpret_cast<const float4*>(x + (size_t)base * F);
        const float4* p1 = reinterpret_cast<const float4*>(x + (size_t)(base + 1) * F);
        #pragma unroll
        for (int q = 0; q < 4; ++q) {
            float4 v0 = p0[q], v1 = p1[q];
            a[4*q+0]=v0.x; a[4*q+1]=v0.y; a[4*q+2]=v0.z; a[4*q+3]=v0.w;
            b[4*q+0]=v1.x; b[4*q+1]=v1.y; b[4*q+2]=v1.z; b[4*q+3]=v1.w;
        }
        #pragma unroll
        for (int k = 0; k < F; ++k) { v2f v = {a[k], b[k]}; xp[k] = v; }
    }

    v2f res = {blin[0], blin[0]};

    // Fully unrolled: 32 independent j-bodies; each has two 16-deep
    // pk-FMA chains (Z,H) + a short transcendental epilogue. Cross-j
    // ILP keeps the VALU fed; scalar weight loads prefetch ahead.
    #pragma unroll
    for (int j = 0; j < HD; ++j) {
        const float bz = bxz[j] + bhz[j];   // uniform -> s_load
        const float bh = bxh[j] + bhh[j];
        v2f aZ = {bz, bz};
        v2f aH = {bh, bh};
        #pragma unroll
        for (int k = 0; k < F; ++k) {
            const float wz = Wxz[k * HD + j];   // uniform -> s_load
            const float wh = Wxh[k * HD + j];
            v2f wz2 = {wz, wz};
            v2f wh2 = {wh, wh};
            aZ = __builtin_elementwise_fma(xp[k], wz2, aZ);
            aH = __builtin_elementwise_fma(xp[k], wh2, aH);
        }
        // relu((1-Z)*tanh(aH)) = max(v-1,0) / ((1+u)(1+v)),
        // u = e^aZ, v = e^{2 aH} (clamped finite).
        const float wl = Wlin[j];
        #pragma unroll
        for (int h = 0; h < 2; ++h) {
            const float az = aZ[h];
            const float ah = aH[h];
            const float u = __expf(az);
            const float v = __expf(fminf(2.f * ah, 87.f));
            const float r = __builtin_amdgcn_rcpf((1.f + u) * (1.f + v));
            const float num = fmaxf(v - 1.f, 0.f);
            res[h] = fmaf(num * r, wl, res[h]);
        }
    }

    // 2 contiguous outputs per thread -> one dwordx2 store.
    float2 o = make_float2(res[0], res[1]);
    *reinterpret_cast<float2*>(out + base) = o;
}

extern "C" void kernel_launch(void* const* d_in, const int* in_sizes, int n_in,
                              void* d_out, int out_size, void* d_ws, size_t ws_size,
                              hipStream_t stream) {
    // setup_inputs order:
    // 0:x 1:edge_index 2:edge_weight 3:Wxz 4:bxz 5:Whz 6:bhz 7:Wxr 8:bxr
    // 9:Whr 10:bhr 11:Wxh 12:bxh 13:Whh 14:bhh 15:Wlin 16:blin
    const float* x    = (const float*)d_in[0];
    const float* Wxz  = (const float*)d_in[3];
    const float* bxz  = (const float*)d_in[4];
    const float* bhz  = (const float*)d_in[6];
    const float* Wxh  = (const float*)d_in[11];
    const float* bxh  = (const float*)d_in[12];
    const float* bhh  = (const float*)d_in[14];
    const float* Wlin = (const float*)d_in[15];
    const float* blin = (const float*)d_in[16];
    float* out = (float*)d_out;

    const int n = in_sizes[0] / F;          // 1,000,000 nodes
    const int threads = n / NPT;            // 500,000
    const int blocks = (threads + 255) / 256;  // 1954
    gru_fused<<<blocks, 256, 0, stream>>>(
        x, Wxz, bxz, bhz, Wxh, bxh, bhh, Wlin, blin, out, n);
}

// Round 2
// 381.771 us; speedup vs baseline: 1.2726x; 1.2726x over previous
//
#include <hip/hip_runtime.h>

// GConvGRU (ChebConv K=1) + ReLU + Linear, fully fused, H0 = 0:
//   Z  = sigmoid(x@Wxz + bxz + bhz)
//   Ht = tanh(x@Wxh + bxh + bhh)          (R-gate cancels: R*H0 = 0)
//   out = relu((1-Z)*Ht) @ Wlin + blin
// edge_index / edge_weight mathematically unused (K=1) -> never read.
//
// R3 changes vs R2 (post-mortem: R2's full unroll + uniform global loads
// made the compiler hoist ~1024 s_loads, overflow the SGPR file, and
// spill via v_writelane/v_readlane -> 18x VALU inflation, 273 us):
//  * Weights staged in LDS once per block (4.5 KB): {wz,wh} float2 pairs
//    k-major, biases pre-folded, Wlin. Inner loop reads them with
//    uniform-address ds_read_b64 (wave broadcast, conflict-free) ->
//    ZERO SGPR pressure, so the full j-unroll is now safe and the
//    scheduler can pipeline ds_reads across j bodies.
//  * NPT back to 4 (R2's NPT=2 doubled weight reads per node - that was
//    the R0 bottleneck R1 fixed).
//  * Per-j epilogue keeps accumulator live range at 8 VGPRs; target
//    <=128 VGPR via __launch_bounds__(256,4).
// Math identical to R1/R2 -> absmax unchanged.

typedef float v2f __attribute__((ext_vector_type(2)));

constexpr int F   = 16;  // F_IN
constexpr int HD  = 32;  // HID
constexpr int NPT = 4;   // nodes per thread

__global__ __launch_bounds__(256, 4) void gru_fused(
    const float* __restrict__ x,
    const float* __restrict__ Wxz, const float* __restrict__ bxz,
    const float* __restrict__ bhz,
    const float* __restrict__ Wxh, const float* __restrict__ bxh,
    const float* __restrict__ bhh,
    const float* __restrict__ Wlin, const float* __restrict__ blin,
    float* __restrict__ out, int n)
{
    __shared__ v2f  sW[F * HD];   // sW[k*HD+j] = {Wxz[k][j], Wxh[k][j]}
    __shared__ v2f  sB[HD];       // {bxz+bhz, bxh+bhh}
    __shared__ float sL[HD];      // Wlin

    const int tid = threadIdx.x;

    // Cooperative stage: 512 weight pairs, coalesced reads.
    #pragma unroll
    for (int i = 0; i < 2; ++i) {
        const int idx = tid + i * 256;           // == k*HD + j, 0..511
        v2f w = { Wxz[idx], Wxh[idx] };
        sW[idx] = w;
    }
    if (tid < HD) {
        v2f b = { bxz[tid] + bhz[tid], bxh[tid] + bhh[tid] };
        sB[tid] = b;
        sL[tid] = Wlin[tid];
    }
    __syncthreads();

    const int t = blockIdx.x * 256 + tid;
    const int base = t * NPT;
    if (base >= n) return;   // after the sync: no barrier divergence

    // Load 4 nodes' features, packed as node-pair v2f:
    // xp[p][k] = { x[node 2p][k], x[node 2p+1][k] }  (64 VGPRs)
    v2f xp[2][F];
    #pragma unroll
    for (int p = 0; p < 2; ++p) {
        const float4* p0 = reinterpret_cast<const float4*>(x + (size_t)(base + 2*p) * F);
        const float4* p1 = reinterpret_cast<const float4*>(x + (size_t)(base + 2*p + 1) * F);
        #pragma unroll
        for (int q = 0; q < 4; ++q) {
            float4 v0 = p0[q], v1 = p1[q];
            v2f a0 = {v0.x, v1.x}; xp[p][4*q+0] = a0;
            v2f a1 = {v0.y, v1.y}; xp[p][4*q+1] = a1;
            v2f a2 = {v0.z, v1.z}; xp[p][4*q+2] = a2;
            v2f a3 = {v0.w, v1.w}; xp[p][4*q+3] = a3;
        }
    }

    const float b0 = blin[0];
    v2f res[2];
    res[0] = (v2f){b0, b0};
    res[1] = (v2f){b0, b0};

    // Full unroll: 32 j-bodies, each two 16-deep pk-FMA chains per node
    // pair + short transcendental epilogue. Weight operands come from
    // LDS broadcasts; no SGPR pressure, cross-j ILP for the scheduler.
    #pragma unroll
    for (int j = 0; j < HD; ++j) {
        const v2f b = sB[j];
        v2f aZ[2], aH[2];
        #pragma unroll
        for (int p = 0; p < 2; ++p) {
            aZ[p] = (v2f){b[0], b[0]};
            aH[p] = (v2f){b[1], b[1]};
        }
        #pragma unroll
        for (int k = 0; k < F; ++k) {
            const v2f w = sW[k * HD + j];        // ds_read_b64, uniform
            const v2f wz = {w[0], w[0]};
            const v2f wh = {w[1], w[1]};
            #pragma unroll
            for (int p = 0; p < 2; ++p) {
                aZ[p] = __builtin_elementwise_fma(xp[p][k], wz, aZ[p]);
                aH[p] = __builtin_elementwise_fma(xp[p][k], wh, aH[p]);
            }
        }
        // relu((1-Z)*tanh(aH)) = max(v-1,0) / ((1+u)(1+v)),
        // u = e^aZ, v = e^{2 aH} (clamped finite).
        const float wl = sL[j];
        #pragma unroll
        for (int p = 0; p < 2; ++p) {
            #pragma unroll
            for (int h = 0; h < 2; ++h) {
                const float az = aZ[p][h];
                const float ah = aH[p][h];
                const float u = __expf(az);
                const float v = __expf(fminf(2.f * ah, 87.f));
                const float r = __builtin_amdgcn_rcpf((1.f + u) * (1.f + v));
                const float num = fmaxf(v - 1.f, 0.f);
                res[p][h] = fmaf(num * r, wl, res[p][h]);
            }
        }
    }

    // 4 contiguous outputs per thread -> one dwordx4 store (16B aligned).
    float4 o = make_float4(res[0][0], res[0][1], res[1][0], res[1][1]);
    *reinterpret_cast<float4*>(out + base) = o;
}

extern "C" void kernel_launch(void* const* d_in, const int* in_sizes, int n_in,
                              void* d_out, int out_size, void* d_ws, size_t ws_size,
                              hipStream_t stream) {
    // setup_inputs order:
    // 0:x 1:edge_index 2:edge_weight 3:Wxz 4:bxz 5:Whz 6:bhz 7:Wxr 8:bxr
    // 9:Whr 10:bhr 11:Wxh 12:bxh 13:Whh 14:bhh 15:Wlin 16:blin
    const float* x    = (const float*)d_in[0];
    const float* Wxz  = (const float*)d_in[3];
    const float* bxz  = (const float*)d_in[4];
    const float* bhz  = (const float*)d_in[6];
    const float* Wxh  = (const float*)d_in[11];
    const float* bxh  = (const float*)d_in[12];
    const float* bhh  = (const float*)d_in[14];
    const float* Wlin = (const float*)d_in[15];
    const float* blin = (const float*)d_in[16];
    float* out = (float*)d_out;

    const int n = in_sizes[0] / F;             // 1,000,000 nodes
    const int threads = n / NPT;               // 250,000
    const int blocks = (threads + 255) / 256;  // 977
    gru_fused<<<blocks, 256, 0, stream>>>(
        x, Wxz, bxz, bhz, Wxh, bxh, bhh, Wlin, blin, out, n);
}

// Round 3
// 267.516 us; speedup vs baseline: 1.8161x; 1.4271x over previous
//
#include <hip/hip_runtime.h>

// GConvGRU (ChebConv K=1) + ReLU + Linear, fully fused, H0 = 0:
//   Z  = sigmoid(x@Wxz + bxz + bhz)
//   Ht = tanh(x@Wxh + bxh + bhh)          (R-gate cancels: R*H0 = 0)
//   out = relu((1-Z)*Ht) @ Wlin + blin
// edge_index / edge_weight mathematically unused (K=1) -> never read.
//
// R4 changes vs R3 (post-mortem: allocator capped VGPRs at 64 while
// NPT=4 needed ~100 -> xp spilled to scratch -> 266/316 MB HBM
// fetch/write vs 68/4 ideal; kernel latency-bound on its own spills):
//  * NPT 4 -> 2: xp[16] v2f = 32 VGPR; total ~55-60 -> fits UNDER the
//    64-cap instead of fighting it. 500k threads -> 7.6 waves/SIMD TLP.
//  * Weight LDS reads as j-PAIRS via 16B loads (v4f = {wz,wh} x 2 j):
//    halves ds_read count vs R3 (256/thread), uniform-address broadcast.
//  * __launch_bounds__(256) only — R3's (256,4) did not raise the cap;
//    design under 64 instead.
//  * #pragma unroll 4 on the j-pair loop: cross-body ILP, ~2KB hot loop.
// Math identical to R1-R3 -> absmax unchanged.

typedef float v2f __attribute__((ext_vector_type(2)));
typedef float v4f __attribute__((ext_vector_type(4)));

constexpr int F   = 16;  // F_IN
constexpr int HD  = 32;  // HID
constexpr int NPT = 2;   // nodes per thread (one v2f lane pair)

__global__ __launch_bounds__(256) void gru_fused(
    const float* __restrict__ x,
    const float* __restrict__ Wxz, const float* __restrict__ bxz,
    const float* __restrict__ bhz,
    const float* __restrict__ Wxh, const float* __restrict__ bxh,
    const float* __restrict__ bhh,
    const float* __restrict__ Wlin, const float* __restrict__ blin,
    float* __restrict__ out, int n)
{
    __shared__ alignas(16) v2f  sW[F * HD];  // sW[k*HD+j] = {Wxz[k][j], Wxh[k][j]}
    __shared__ alignas(16) v2f  sB[HD];      // {bxz+bhz, bxh+bhh}
    __shared__ alignas(16) float sL[HD];     // Wlin

    const int tid = threadIdx.x;

    // Cooperative stage: 512 weight pairs, coalesced dword reads.
    #pragma unroll
    for (int i = 0; i < 2; ++i) {
        const int idx = tid + i * 256;          // == k*HD + j, 0..511
        sW[idx] = (v2f){ Wxz[idx], Wxh[idx] };
    }
    if (tid < HD) {
        sB[tid] = (v2f){ bxz[tid] + bhz[tid], bxh[tid] + bhh[tid] };
        sL[tid] = Wlin[tid];
    }
    __syncthreads();

    const int t = blockIdx.x * 256 + tid;
    const int base = t * NPT;
    if (base >= n) return;   // after the sync: no barrier divergence

    // Two nodes' features = 128 contiguous bytes per thread (coalesced),
    // packed as 16 v2f node-pairs: xp[k] = { x[n0][k], x[n1][k] }.
    v2f xp[F];
    {
        const float4* px = reinterpret_cast<const float4*>(x + (size_t)base * F);
        float4 n0[4], n1[4];
        #pragma unroll
        for (int q = 0; q < 4; ++q) { n0[q] = px[q]; n1[q] = px[q + 4]; }
        #pragma unroll
        for (int q = 0; q < 4; ++q) {
            xp[4*q+0] = (v2f){n0[q].x, n1[q].x};
            xp[4*q+1] = (v2f){n0[q].y, n1[q].y};
            xp[4*q+2] = (v2f){n0[q].z, n1[q].z};
            xp[4*q+3] = (v2f){n0[q].w, n1[q].w};
        }
    }

    const float b0 = blin[0];
    v2f res = {b0, b0};

    // j-pairs: one ds_read_b128 per k covers both gates x two j's.
    // Live regs per body: 8 acc + 4 weight temp; xp(32) persists.
    #pragma unroll 4
    for (int jp = 0; jp < HD / 2; ++jp) {
        const v4f bb = *reinterpret_cast<const v4f*>(&sB[2 * jp]);
        v2f aZ[2], aH[2];
        aZ[0] = (v2f){bb[0], bb[0]};  aH[0] = (v2f){bb[1], bb[1]};
        aZ[1] = (v2f){bb[2], bb[2]};  aH[1] = (v2f){bb[3], bb[3]};
        #pragma unroll
        for (int k = 0; k < F; ++k) {
            const v4f w = *reinterpret_cast<const v4f*>(&sW[k * HD + 2 * jp]);
            const v2f xk = xp[k];
            aZ[0] = __builtin_elementwise_fma(xk, (v2f){w[0], w[0]}, aZ[0]);
            aH[0] = __builtin_elementwise_fma(xk, (v2f){w[1], w[1]}, aH[0]);
            aZ[1] = __builtin_elementwise_fma(xk, (v2f){w[2], w[2]}, aZ[1]);
            aH[1] = __builtin_elementwise_fma(xk, (v2f){w[3], w[3]}, aH[1]);
        }
        // relu((1-Z)*tanh(aH)) = max(v-1,0) / ((1+u)(1+v)),
        // u = e^aZ, v = e^{2 aH} (clamped finite).
        const v2f wl = *reinterpret_cast<const v2f*>(&sL[2 * jp]);
        #pragma unroll
        for (int jj = 0; jj < 2; ++jj) {
            #pragma unroll
            for (int h = 0; h < 2; ++h) {
                const float az = aZ[jj][h];
                const float ah = aH[jj][h];
                const float u = __expf(az);
                const float v = __expf(fminf(2.f * ah, 87.f));
                const float r = __builtin_amdgcn_rcpf((1.f + u) * (1.f + v));
                const float num = fmaxf(v - 1.f, 0.f);
                res[h] = fmaf(num * r, wl[jj], res[h]);
            }
        }
    }

    // 2 contiguous outputs per thread -> one dwordx2 store.
    *reinterpret_cast<float2*>(out + base) = make_float2(res[0], res[1]);
}

extern "C" void kernel_launch(void* const* d_in, const int* in_sizes, int n_in,
                              void* d_out, int out_size, void* d_ws, size_t ws_size,
                              hipStream_t stream) {
    // setup_inputs order:
    // 0:x 1:edge_index 2:edge_weight 3:Wxz 4:bxz 5:Whz 6:bhz 7:Wxr 8:bxr
    // 9:Whr 10:bhr 11:Wxh 12:bxh 13:Whh 14:bhh 15:Wlin 16:blin
    const float* x    = (const float*)d_in[0];
    const float* Wxz  = (const float*)d_in[3];
    const float* bxz  = (const float*)d_in[4];
    const float* bhz  = (const float*)d_in[6];
    const float* Wxh  = (const float*)d_in[11];
    const float* bxh  = (const float*)d_in[12];
    const float* bhh  = (const float*)d_in[14];
    const float* Wlin = (const float*)d_in[15];
    const float* blin = (const float*)d_in[16];
    float* out = (float*)d_out;

    const int n = in_sizes[0] / F;             // 1,000,000 nodes
    const int threads = n / NPT;               // 500,000
    const int blocks = (threads + 255) / 256;  // 1954
    gru_fused<<<blocks, 256, 0, stream>>>(
        x, Wxz, bxz, bhz, Wxh, bxh, bhh, Wlin, blin, out, n);
}

// Round 4
// 264.084 us; speedup vs baseline: 1.8397x; 1.0130x over previous
//
#include <hip/hip_runtime.h>

// GConvGRU (ChebConv K=1) + ReLU + Linear, fully fused, H0 = 0:
//   Z  = sigmoid(x@Wxz + bxz + bhz)
//   Ht = tanh(x@Wxh + bxh + bhh)          (R-gate cancels: R*H0 = 0)
//   out = relu((1-Z)*Ht) @ Wlin + blin
// edge_index / edge_weight mathematically unused (K=1) -> never read.
//
// R5 changes vs R4 (post-mortem: R4 == R1 == ~57us kernel; largest
// identified consumer is the per-CU LDS pipe serving 256 uniform
// ds_read_b128 per THREAD (~26us at ~8cyc/broadcast, 30.5 waves/CU).
// Weight-fetch cost scales per-thread, so amortize over more nodes):
//  * NPT 2 -> 4: same 256 ds_reads now cover 4 nodes -> per-node LDS
//    work halves. VALU/VMEM per node unchanged.
//  * __launch_bounds__(256, 2): R3's spill was the allocator capping at
//    64 VGPR; cap is now 256 so the ~100-VGPR footprint (xp 64 + acc 16
//    + temps) allocates cleanly -> 4 waves/SIMD, matching the 3.8-wave
//    grid (3906 waves / 1024 SIMDs, single generation).
//  * H-gate weights/biases pre-scaled by 2.0 at stage time (exact, no
//    rounding change): epilogue drops the 2.f*ah mul (128/thread).
//  * #pragma unroll 2 on the jp loop (body has 8 indep. 16-deep FMA
//    chains; unroll 2 lets next body's ds_reads issue under epilogue).
// Math identical (x2.0 fold is exact) -> absmax unchanged.

typedef float v2f __attribute__((ext_vector_type(2)));
typedef float v4f __attribute__((ext_vector_type(4)));

constexpr int F   = 16;  // F_IN
constexpr int HD  = 32;  // HID
constexpr int NPT = 4;   // nodes per thread (two v2f lane pairs)

__global__ __launch_bounds__(256, 2) void gru_fused(
    const float* __restrict__ x,
    const float* __restrict__ Wxz, const float* __restrict__ bxz,
    const float* __restrict__ bhz,
    const float* __restrict__ Wxh, const float* __restrict__ bxh,
    const float* __restrict__ bhh,
    const float* __restrict__ Wlin, const float* __restrict__ blin,
    float* __restrict__ out, int n)
{
    __shared__ alignas(16) v2f  sW[F * HD];  // sW[k*HD+j] = {Wxz[k][j], 2*Wxh[k][j]}
    __shared__ alignas(16) v2f  sB[HD];      // {bxz+bhz, 2*(bxh+bhh)}
    __shared__ alignas(16) float sL[HD];     // Wlin

    const int tid = threadIdx.x;

    // Cooperative stage: 512 weight pairs, coalesced dword reads.
    // H-gate side pre-scaled by 2.0 (exact power of two).
    #pragma unroll
    for (int i = 0; i < 2; ++i) {
        const int idx = tid + i * 256;          // == k*HD + j, 0..511
        sW[idx] = (v2f){ Wxz[idx], 2.0f * Wxh[idx] };
    }
    if (tid < HD) {
        sB[tid] = (v2f){ bxz[tid] + bhz[tid], 2.0f * (bxh[tid] + bhh[tid]) };
        sL[tid] = Wlin[tid];
    }
    __syncthreads();

    const int t = blockIdx.x * 256 + tid;
    const int base = t * NPT;
    if (base >= n) return;   // after the sync: no barrier divergence

    // Four nodes' features = 256 contiguous bytes per thread, packed as
    // node-pair v2f: xp[p][k] = { x[2p][k], x[2p+1][k] }  (64 VGPRs).
    v2f xp[2][F];
    {
        const float4* px = reinterpret_cast<const float4*>(x + (size_t)base * F);
        #pragma unroll
        for (int p = 0; p < 2; ++p) {
            float4 n0[4], n1[4];
            #pragma unroll
            for (int q = 0; q < 4; ++q) { n0[q] = px[8*p + q]; n1[q] = px[8*p + q + 4]; }
            #pragma unroll
            for (int q = 0; q < 4; ++q) {
                xp[p][4*q+0] = (v2f){n0[q].x, n1[q].x};
                xp[p][4*q+1] = (v2f){n0[q].y, n1[q].y};
                xp[p][4*q+2] = (v2f){n0[q].z, n1[q].z};
                xp[p][4*q+3] = (v2f){n0[q].w, n1[q].w};
            }
        }
    }

    const float b0 = blin[0];
    v2f res[2];
    res[0] = (v2f){b0, b0};
    res[1] = (v2f){b0, b0};

    // j-pairs: one ds_read_b128 per k covers both gates x two j's x all
    // four nodes. Live per body: 16 acc + 4 weight temp; xp(64) persists.
    #pragma unroll 2
    for (int jp = 0; jp < HD / 2; ++jp) {
        const v4f bb = *reinterpret_cast<const v4f*>(&sB[2 * jp]);
        v2f aZ[2][2], aH[2][2];   // [j][pair]
        #pragma unroll
        for (int p = 0; p < 2; ++p) {
            aZ[0][p] = (v2f){bb[0], bb[0]};  aH[0][p] = (v2f){bb[1], bb[1]};
            aZ[1][p] = (v2f){bb[2], bb[2]};  aH[1][p] = (v2f){bb[3], bb[3]};
        }
        #pragma unroll
        for (int k = 0; k < F; ++k) {
            const v4f w = *reinterpret_cast<const v4f*>(&sW[k * HD + 2 * jp]);
            const v2f wz0 = {w[0], w[0]}, wh0 = {w[1], w[1]};
            const v2f wz1 = {w[2], w[2]}, wh1 = {w[3], w[3]};
            #pragma unroll
            for (int p = 0; p < 2; ++p) {
                const v2f xk = xp[p][k];
                aZ[0][p] = __builtin_elementwise_fma(xk, wz0, aZ[0][p]);
                aH[0][p] = __builtin_elementwise_fma(xk, wh0, aH[0][p]);
                aZ[1][p] = __builtin_elementwise_fma(xk, wz1, aZ[1][p]);
                aH[1][p] = __builtin_elementwise_fma(xk, wh1, aH[1][p]);
            }
        }
        // relu((1-Z)*tanh) = max(v-1,0) / ((1+u)(1+v)),
        // u = e^aZ, v = e^{aH} (aH pre-scaled by 2; clamp keeps v finite).
        const v2f wl = *reinterpret_cast<const v2f*>(&sL[2 * jp]);
        #pragma unroll
        for (int jj = 0; jj < 2; ++jj) {
            #pragma unroll
            for (int p = 0; p < 2; ++p) {
                #pragma unroll
                for (int h = 0; h < 2; ++h) {
                    const float az = aZ[jj][p][h];
                    const float ah = aH[jj][p][h];
                    const float u = __expf(az);
                    const float v = __expf(fminf(ah, 87.f));
                    const float r = __builtin_amdgcn_rcpf((1.f + u) * (1.f + v));
                    const float num = fmaxf(v - 1.f, 0.f);
                    res[p][h] = fmaf(num * r, wl[jj], res[p][h]);
                }
            }
        }
    }

    // 4 contiguous outputs per thread -> one dwordx4 store (16B aligned).
    float4 o = make_float4(res[0][0], res[0][1], res[1][0], res[1][1]);
    *reinterpret_cast<float4*>(out + base) = o;
}

extern "C" void kernel_launch(void* const* d_in, const int* in_sizes, int n_in,
                              void* d_out, int out_size, void* d_ws, size_t ws_size,
                              hipStream_t stream) {
    // setup_inputs order:
    // 0:x 1:edge_index 2:edge_weight 3:Wxz 4:bxz 5:Whz 6:bhz 7:Wxr 8:bxr
    // 9:Whr 10:bhr 11:Wxh 12:bxh 13:Whh 14:bhh 15:Wlin 16:blin
    const float* x    = (const float*)d_in[0];
    const float* Wxz  = (const float*)d_in[3];
    const float* bxz  = (const float*)d_in[4];
    const float* bhz  = (const float*)d_in[6];
    const float* Wxh  = (const float*)d_in[11];
    const float* bxh  = (const float*)d_in[12];
    const float* bhh  = (const float*)d_in[14];
    const float* Wlin = (const float*)d_in[15];
    const float* blin = (const float*)d_in[16];
    float* out = (float*)d_out;

    const int n = in_sizes[0] / F;             // 1,000,000 nodes
    const int threads = n / NPT;               // 250,000
    const int blocks = (threads + 255) / 256;  // 977
    gru_fused<<<blocks, 256, 0, stream>>>(
        x, Wxz, bxz, bhz, Wxh, bxh, bhh, Wlin, blin, out, n);
}